// Round 11
// baseline (352.194 us; speedup 1.0000x reference)
//
#include <hip/hip_runtime.h>
#include <hip/hip_bf16.h>

typedef short bf16x8 __attribute__((ext_vector_type(8)));
typedef float f32x4 __attribute__((ext_vector_type(4)));
typedef int int4v __attribute__((ext_vector_type(4)));

#define OMEGA 30.0f
#define NBLK 512

// sin(30*z) via HW v_sin: 3 VALU ops. |30z| small (SIREN), err ~1e-6 << bf16 lsb.
__device__ __forceinline__ float fast_sin30(float z) {
  float t = z * 4.7746483f;  // 30/(2*pi)
  t = __builtin_amdgcn_fractf(t);
  return __builtin_amdgcn_sinf(t);
}

// device-scope grid barrier: cnt at bar[0], gen at bar[16] (separate lines).
__device__ __forceinline__ void gbar(int* bar, int& mygen) {
  __syncthreads();
  if (threadIdx.x == 0) {
    int g = mygen + 1;
    if (__hip_atomic_fetch_add(&bar[0], 1, __ATOMIC_ACQ_REL, __HIP_MEMORY_SCOPE_AGENT) == NBLK - 1) {
      __hip_atomic_store(&bar[0], 0, __ATOMIC_RELAXED, __HIP_MEMORY_SCOPE_AGENT);
      __hip_atomic_store(&bar[16], g, __ATOMIC_RELEASE, __HIP_MEMORY_SCOPE_AGENT);
    } else {
      while (__hip_atomic_load(&bar[16], __ATOMIC_ACQUIRE, __HIP_MEMORY_SCOPE_AGENT) < g)
        __builtin_amdgcn_s_sleep(2);
    }
    mygen = g;
  }
  __syncthreads();
}

__global__ void k_init(int* bar) {
  bar[0] = 0;
  bar[16] = 0;
}

// ---------------- mega: prep -> gbar -> conv -> gbar -> fused ----------------
__global__ __launch_bounds__(256) void k_mega(const float* __restrict__ xi,
                                              const float* __restrict__ W0,
                                              const float* __restrict__ b0,
                                              const float* __restrict__ b1,
                                              const float* __restrict__ b2,
                                              const float* __restrict__ W3,
                                              const float* __restrict__ b3,
                                              const float* __restrict__ W1,
                                              const float* __restrict__ W2,
                                              __hip_bfloat16* __restrict__ xt,
                                              __hip_bfloat16* __restrict__ wt2,
                                              __hip_bfloat16* __restrict__ w1t,
                                              __hip_bfloat16* __restrict__ w2t,
                                              __hip_bfloat16* __restrict__ h0,
                                              float* __restrict__ out,
                                              int* bar) {
  __shared__ __align__(16) char SMEM[47104];
  int bid = blockIdx.x;
  int tid = threadIdx.x;
  int mygen = 0;

  // ================= PHASE 1: prep =================
  {
    float(*tile)[33] = reinterpret_cast<float(*)[33]>(SMEM);
    // 8 transpose tiles per block: xi [B,C,H,W] f32 -> xt [B,HW,C] bf16
    int r = tid >> 5, cc = tid & 31;
    for (int i8 = 0; i8 < 8; ++i8) {
      int bx = (bid << 3) + i8;
      int b = bx >> 11, c0 = ((bx >> 9) & 3) << 5, hw0 = (bx & 511) << 5;
      const float* src = xi + (((size_t)b * 128 + c0) << 14) + hw0;
      float v[4];
#pragma unroll
      for (int i = 0; i < 4; ++i) v[i] = src[(size_t)(r + i * 8) * 16384 + cc];
      __syncthreads();
#pragma unroll
      for (int i = 0; i < 4; ++i) tile[r + i * 8][cc] = v[i];
      __syncthreads();
      __hip_bfloat16* dst = xt + (((size_t)b * 16384 + hw0) << 7) + c0;
#pragma unroll
      for (int i = 0; i < 4; ++i)
        dst[(size_t)(r + i * 8) * 128 + cc] = __float2bfloat16(tile[cc][r + i * 8]);
    }
    __syncthreads();
    if (bid < 200) {
      // W0 rows 0..3199 -> wt2[f][n][c] = W0[c*25+f][n]
      int f = bid >> 3, nb = bid & 7;
      int nn = tid & 31, cr = tid >> 5;
#pragma unroll
      for (int i = 0; i < 16; ++i) {
        int c = cr * 16 + i;
        tile[c][nn] = W0[(size_t)(c * 25 + f) * 256 + nb * 32 + nn];
      }
      __syncthreads();
#pragma unroll
      for (int i = 0; i < 16; ++i) {
        int idx = i * 256 + tid;
        int n = idx >> 7, c = idx & 127;
        wt2[(size_t)f * 32768 + (size_t)(nb * 32 + n) * 128 + c] = __float2bfloat16(tile[c][n]);
      }
    } else if (bid < 328) {
      // w1t[n][k] = W1[k][n]; w2t likewise
      int rI = bid - 200;
      const float* src = (rI >> 6) ? W2 : W1;
      __hip_bfloat16* dst = (rI >> 6) ? w2t : w1t;
      int k0 = ((rI >> 3) & 7) << 5, n0 = (rI & 7) << 5;
#pragma unroll
      for (int i = 0; i < 4; ++i)
        tile[r + i * 8][cc] = src[(size_t)(k0 + r + i * 8) * 256 + n0 + cc];
      __syncthreads();
#pragma unroll
      for (int i = 0; i < 4; ++i)
        dst[(size_t)(n0 + r + i * 8) * 256 + k0 + cc] = __float2bfloat16(tile[cc][r + i * 8]);
    }
  }

  gbar(bar, mygen);

  // ================= PHASE 2: conv (round-10 body, bid -> bx,n0) =================
  {
    char* Al = SMEM;            // [240 pos][64ch] swz, 30720 B
    char* Bl = SMEM + 30720;    // 2 x [64 n][64ch] swz, 16384 B
    int bx = bid & 127;
    int b = bx >> 6, tr = (bx >> 3) & 7, tc = bx & 7;
    int n0 = (bid >> 7) << 6;
    int lane = tid & 63, wave = tid >> 6;
    int lr = lane & 15, lg = lane >> 4;

    float wA[4], wB[4], bb[4];
#pragma unroll
    for (int ni = 0; ni < 4; ++ni) {
      int n = n0 + (ni << 4) + lr;
      wA[ni] = W0[3200 * 256 + n];
      wB[ni] = W0[3201 * 256 + n];
      bb[ni] = b0[n];
    }

    int4v breg[2];
    auto loadB = [&](int i) {
      int cb = (i / 25) & 1, f = i % 25;
#pragma unroll
      for (int j = 0; j < 2; ++j) {
        int idx = j * 256 + tid;
        int n = idx >> 3, s = idx & 7;
        breg[j] = *(const int4v*)(wt2 + (size_t)(f * 256 + n0 + n) * 128 + cb * 64 + s * 8);
      }
    };
    auto writeB = [&](int i) {
      char* dst = Bl + (i & 1) * 8192;
#pragma unroll
      for (int j = 0; j < 2; ++j) {
        int idx = j * 256 + tid;
        int n = idx >> 3, s = idx & 7;
        *(int4v*)(dst + n * 128 + ((s ^ (n & 7)) << 4)) = breg[j];
      }
    };

    loadB(0);
    writeB(0);
    loadB(1);

    f32x4 acc[2][4] = {};

    for (int rh = 0; rh < 2; ++rh) {
      for (int half = 0; half < 2; ++half) {
        __syncthreads();
#pragma unroll
        for (int ii = 0; ii < 8; ++ii) {
          int idx = ii * 256 + tid;
          if (idx < 1920) {
            int pos = idx >> 3, s = idx & 7;
            int py = pos / 20, px_ = pos - py * 20;
            int gh = (tr << 4) + (rh << 3) + py - 2, gw = (tc << 4) + px_ - 2;
            int4v v = {0, 0, 0, 0};
            if ((unsigned)gh < 128u && (unsigned)gw < 128u)
              v = *(const int4v*)(xt + (((size_t)((b << 14) + (gh << 7) + gw)) << 7) + half * 64 + s * 8);
            *(int4v*)(Al + pos * 128 + ((s ^ (pos & 7)) << 4)) = v;
          }
        }
        __syncthreads();

        for (int f = 0; f < 25; ++f) {
          int i = rh * 50 + half * 25 + f;
          if (i < 99) writeB(i + 1);
          if (i < 98) loadB(i + 2);
          int fy = f / 5, fx = f - fy * 5;
          int px = lr + fx;
          char* Bbuf = Bl + (i & 1) * 8192;
#pragma unroll
          for (int ks = 0; ks < 2; ++ks) {
            int sk = (ks << 2) + lg;
            bf16x8 a[2], bw[4];
#pragma unroll
            for (int mi = 0; mi < 2; ++mi) {
              int fl = wave + (mi << 2);
              int pos = (fl + fy) * 20 + px;
              a[mi] = *(const bf16x8*)(Al + pos * 128 + ((sk ^ (pos & 7)) << 4));
            }
#pragma unroll
            for (int ni = 0; ni < 4; ++ni) {
              int nr = (ni << 4) + lr;
              bw[ni] = *(const bf16x8*)(Bbuf + nr * 128 + ((sk ^ (nr & 7)) << 4));
            }
#pragma unroll
            for (int mi = 0; mi < 2; ++mi)
#pragma unroll
              for (int ni = 0; ni < 4; ++ni)
                acc[mi][ni] = __builtin_amdgcn_mfma_f32_16x16x32_bf16(a[mi], bw[ni], acc[mi][ni], 0, 0, 0);
          }
          __syncthreads();
        }
      }

      char* stg = Al + wave * 4096;
#pragma unroll
      for (int mi = 0; mi < 2; ++mi) {
        int fl = wave + (mi << 2);
        int H = (tr << 4) + (rh << 3) + fl;
        float gy = -1.f + (2.f / 127.f) * (float)H;
#pragma unroll
        for (int j = 0; j < 4; ++j) {
          int cpx = (lg << 2) + j;
          int W = (tc << 4) + cpx;
          float gx = -1.f + (2.f / 127.f) * (float)W;
#pragma unroll
          for (int ni = 0; ni < 4; ++ni) {
            float v = acc[mi][ni][j] + bb[ni] + gx * wA[ni] + gy * wB[ni];
            unsigned short bits = __hip_bfloat16_raw(__float2bfloat16(fast_sin30(v))).x;
            int n = (ni << 4) + lr;
            int c = n >> 3;
            *(unsigned short*)(stg + mi * 2048 + cpx * 128 + (((c ^ (cpx & 7)) << 4) | ((n & 7) << 1))) = bits;
          }
        }
      }
#pragma unroll
      for (int mi = 0; mi < 2; ++mi) {
        int fl = wave + (mi << 2);
        int H = (tr << 4) + (rh << 3) + fl;
#pragma unroll
        for (int i2 = 0; i2 < 2; ++i2) {
          int r2 = (i2 << 3) + (lane >> 3);
          int c = lane & 7;
          int4v v = *(const int4v*)(stg + mi * 2048 + r2 * 128 + ((c ^ (r2 & 7)) << 4));
          int m = (b << 14) + (H << 7) + (tc << 4) + r2;
          *(int4v*)(h0 + (size_t)m * 256 + n0 + c * 8) = v;
        }
      }
      if (rh == 0) {
#pragma unroll
        for (int mi = 0; mi < 2; ++mi)
#pragma unroll
          for (int ni = 0; ni < 4; ++ni)
            acc[mi][ni] = f32x4{0.f, 0.f, 0.f, 0.f};
      }
    }
  }

  gbar(bar, mygen);

  // ================= PHASE 3: fused MLP, 2 x 32-pixel units per block =================
  {
    char* Hl = SMEM;                       // [32 r][512 B] swz
    float* w3l = (float*)(SMEM + 16384);   // 768 floats
    int lane = tid & 63, wave = tid >> 6;
    int lr = lane & 15, lg = lane >> 4;
    int mg = wave >> 1, nh = wave & 1;

    for (int i = tid; i < 768; i += 256) w3l[i] = W3[i];

    const char* pB1[8];
    const char* pB2[8];
    float bb1[8], bb2[8];
#pragma unroll
    for (int ni = 0; ni < 8; ++ni) {
      int n = (nh << 7) + (ni << 4) + lr;
      pB1[ni] = (const char*)(w1t + ((size_t)n << 8)) + (lg << 4);
      pB2[ni] = (const char*)(w2t + ((size_t)n << 8)) + (lg << 4);
      bb1[ni] = b1[n];
      bb2[ni] = b2[n];
    }

    for (int u = 0; u < 2; ++u) {
      int m0 = ((bid << 1) + u) << 5;
      __syncthreads();  // Hl reuse safe (prior unit/phase readers done)

      int mrow = m0 + (mg << 4) + lr;
      const char* pA0 = (const char*)(h0 + ((size_t)mrow << 8)) + (lg << 4);

      f32x4 acc[8] = {};
#pragma unroll
      for (int ks = 0; ks < 8; ++ks) {
        bf16x8 a = *(const bf16x8*)(pA0 + ks * 64);
        bf16x8 bw[8];
#pragma unroll
        for (int ni = 0; ni < 8; ++ni) bw[ni] = *(const bf16x8*)(pB1[ni] + ks * 64);
#pragma unroll
        for (int ni = 0; ni < 8; ++ni)
          acc[ni] = __builtin_amdgcn_mfma_f32_16x16x32_bf16(a, bw[ni], acc[ni], 0, 0, 0);
      }
#pragma unroll
      for (int j = 0; j < 4; ++j) {
        int r = (mg << 4) + (lg << 2) + j;
#pragma unroll
        for (int ni = 0; ni < 8; ++ni) {
          int c = (nh << 7) + (ni << 4) + lr;
          unsigned short bits =
              __hip_bfloat16_raw(__float2bfloat16(fast_sin30(acc[ni][j] + bb1[ni]))).x;
          int sl = (c >> 3) ^ (r & 31);
          *(unsigned short*)(Hl + r * 512 + (sl << 4) + ((c & 7) << 1)) = bits;
        }
      }
      __syncthreads();

      int rA = (mg << 4) + lr;
      f32x4 acc2[8] = {};
#pragma unroll
      for (int ks = 0; ks < 8; ++ks) {
        int sk = (ks << 2) + lg;
        bf16x8 a = *(const bf16x8*)(Hl + rA * 512 + ((sk ^ (rA & 31)) << 4));
        bf16x8 bw[8];
#pragma unroll
        for (int ni = 0; ni < 8; ++ni) bw[ni] = *(const bf16x8*)(pB2[ni] + ks * 64);
#pragma unroll
        for (int ni = 0; ni < 8; ++ni)
          acc2[ni] = __builtin_amdgcn_mfma_f32_16x16x32_bf16(a, bw[ni], acc2[ni], 0, 0, 0);
      }
      __syncthreads();
#pragma unroll
      for (int j = 0; j < 4; ++j) {
        int r = (mg << 4) + (lg << 2) + j;
#pragma unroll
        for (int ni = 0; ni < 8; ++ni) {
          int c = (nh << 7) + (ni << 4) + lr;
          unsigned short bits =
              __hip_bfloat16_raw(__float2bfloat16(fast_sin30(acc2[ni][j] + bb2[ni]))).x;
          int sl = (c >> 3) ^ (r & 31);
          *(unsigned short*)(Hl + r * 512 + (sl << 4) + ((c & 7) << 1)) = bits;
        }
      }
      __syncthreads();

      int pix = tid >> 3, s = tid & 7;
      float a0 = 0.f, a1 = 0.f, a2 = 0.f;
#pragma unroll
      for (int q = 0; q < 4; ++q) {
        int sl = ((s << 2) + q) ^ (pix & 31);
        bf16x8 hv = *(const bf16x8*)(Hl + pix * 512 + (sl << 4));
#pragma unroll
        for (int e = 0; e < 8; ++e) {
          int k = (s << 5) + (q << 3) + e;
          float h = __uint_as_float((unsigned)(unsigned short)hv[e] << 16);
          a0 += h * w3l[k * 3 + 0];
          a1 += h * w3l[k * 3 + 1];
          a2 += h * w3l[k * 3 + 2];
        }
      }
#pragma unroll
      for (int d = 1; d < 8; d <<= 1) {
        a0 += __shfl_xor(a0, d);
        a1 += __shfl_xor(a1, d);
        a2 += __shfl_xor(a2, d);
      }
      if (s < 3) {
        int m = m0 + pix;
        int b = m >> 14, hw = m & 16383;
        float v = (s == 0) ? (a0 + b3[0]) : (s == 1) ? (a1 + b3[1]) : (a2 + b3[2]);
        out[((b * 3 + s) << 14) + hw] = v;
      }
    }
  }
}

extern "C" void kernel_launch(void* const* d_in, const int* in_sizes, int n_in,
                              void* d_out, int out_size, void* d_ws, size_t ws_size,
                              hipStream_t stream) {
  const float* xi = (const float*)d_in[0];
  const float* W0 = (const float*)d_in[1];
  const float* b0 = (const float*)d_in[2];
  const float* W1 = (const float*)d_in[3];
  const float* b1 = (const float*)d_in[4];
  const float* W2 = (const float*)d_in[5];
  const float* b2 = (const float*)d_in[6];
  const float* W3 = (const float*)d_in[7];
  const float* b3 = (const float*)d_in[8];
  float* out = (float*)d_out;
  char* ws = (char*)d_ws;

  __hip_bfloat16* xt  = (__hip_bfloat16*)(ws + 0);          //  8,388,608 B
  __hip_bfloat16* wt2 = (__hip_bfloat16*)(ws + 8388608);    //  1,638,400 B
  __hip_bfloat16* w1t = (__hip_bfloat16*)(ws + 10027008);   //    131,072 B
  __hip_bfloat16* w2t = (__hip_bfloat16*)(ws + 10158080);   //    131,072 B
  __hip_bfloat16* h0  = (__hip_bfloat16*)(ws + 10289152);   // 16,777,216 B
  int* bar            = (int*)(ws + 27066368);              //        128 B

  k_init<<<1, 1, 0, stream>>>(bar);
  k_mega<<<NBLK, 256, 0, stream>>>(xi, W0, b0, b1, b2, W3, b3, W1, W2,
                                   xt, wt2, w1t, w2t, h0, out, bar);
}

// Round 12
// 204.707 us; speedup vs baseline: 1.7205x; 1.7205x over previous
//
#include <hip/hip_runtime.h>
#include <hip/hip_bf16.h>

typedef short bf16x8 __attribute__((ext_vector_type(8)));
typedef float f32x4 __attribute__((ext_vector_type(4)));
typedef int int4v __attribute__((ext_vector_type(4)));

#define OMEGA 30.0f

// sin(30*z) via HW v_sin: 3 VALU ops. |30z| small (SIREN), err ~1e-6 << bf16 lsb.
__device__ __forceinline__ float fast_sin30(float z) {
  float t = z * 4.7746483f;  // 30/(2*pi)
  t = __builtin_amdgcn_fractf(t);
  return __builtin_amdgcn_sinf(t);
}

__device__ __forceinline__ unsigned short f2bf(float x) {
  return __hip_bfloat16_raw(__float2bfloat16(x)).x;
}

// ---------------- prep: all-vectorized (16B stores everywhere) ----------------
// grid 1352: [0,1024) xi-transpose 32hw x 128c; [1024,1224) W0 repack; [1224,1352) W1/W2 T.
__global__ __launch_bounds__(256) void k_prep(const float* __restrict__ xi,
                                              const float* __restrict__ W0,
                                              const float* __restrict__ W1,
                                              const float* __restrict__ W2,
                                              __hip_bfloat16* __restrict__ xt,
                                              __hip_bfloat16* __restrict__ wt2,
                                              __hip_bfloat16* __restrict__ w1t,
                                              __hip_bfloat16* __restrict__ w2t) {
  __shared__ float lds[128][33];
  int bid = blockIdx.x, t = threadIdx.x;
  if (bid < 1024) {
    // xi [B,C,HW] f32 -> xt [B,HW,C] bf16 ; tile = 32 hw x 128 c
    int b = bid >> 9, hw0 = (bid & 511) << 5;
    int cc = t & 31, cr = t >> 5;  // cc: hw-offset, cr: c-group
#pragma unroll
    for (int i = 0; i < 16; ++i) {
      int c = cr * 16 + i;
      lds[c][cc] = xi[(((size_t)(b * 128 + c)) << 14) + hw0 + cc];
    }
    __syncthreads();
    int cg = t & 15;
#pragma unroll
    for (int it = 0; it < 2; ++it) {
      int hw = (t >> 4) + (it << 4);
      bf16x8 v;
#pragma unroll
      for (int w = 0; w < 8; ++w) v[w] = (short)f2bf(lds[cg * 8 + w][hw]);
      *(bf16x8*)(xt + (((size_t)((b << 14) + hw0 + hw)) << 7) + cg * 8) = v;
    }
  } else if (bid < 1224) {
    // W0 rows 0..3199 -> wt2[f][n][c] = W0[c*25+f][n]
    int q = bid - 1024, f = q >> 3, nb = q & 7;
    int nn = t & 31, cr = t >> 5;
#pragma unroll
    for (int i = 0; i < 16; ++i) {
      int c = cr * 16 + i;
      lds[c][nn] = W0[(size_t)(c * 25 + f) * 256 + nb * 32 + nn];
    }
    __syncthreads();
    int cg = t & 15;
#pragma unroll
    for (int it = 0; it < 2; ++it) {
      int n = (t >> 4) + (it << 4);
      bf16x8 v;
#pragma unroll
      for (int w = 0; w < 8; ++w) v[w] = (short)f2bf(lds[cg * 8 + w][n]);
      *(bf16x8*)(wt2 + (size_t)f * 32768 + (size_t)(nb * 32 + n) * 128 + cg * 8) = v;
    }
  } else {
    // w1t[n][k] = W1[k][n]; w2t likewise ; tile 32k x 32n
    int rI = bid - 1224;
    const float* src = (rI >> 6) ? W2 : W1;
    __hip_bfloat16* dst = (rI >> 6) ? w2t : w1t;
    int k0 = ((rI >> 3) & 7) << 5, n0 = (rI & 7) << 5;
    int cc = t & 31, r = t >> 5;
#pragma unroll
    for (int i = 0; i < 4; ++i)
      lds[r + i * 8][cc] = src[(size_t)(k0 + r + i * 8) * 256 + n0 + cc];
    __syncthreads();
    if (t < 128) {
      int kg = t & 3, n = t >> 2;
      bf16x8 v;
#pragma unroll
      for (int w = 0; w < 8; ++w) v[w] = (short)f2bf(lds[kg * 8 + w][n]);
      *(bf16x8*)(dst + (size_t)(n0 + n) * 256 + k0 + kg * 8) = v;
    }
  }
}

// ---------------- conv 5x5 (128->256) + coords + bias + sin ----------------
// grid (128, 4), block 256. LDS 63488 B -> 2 blocks/CU. 2 taps per iteration:
// 52 pair-iters (4 quarters x 13: 12 pairs + 1 single), ONE barrier per iter.
__global__ __launch_bounds__(256) void k_conv(const __hip_bfloat16* __restrict__ xt,
                                              const __hip_bfloat16* __restrict__ wt2,
                                              const float* __restrict__ W0,
                                              const float* __restrict__ b0,
                                              __hip_bfloat16* __restrict__ h0) {
  __shared__ __align__(16) char Al[240 * 128];      // [12 rows x 20 px][64ch], swz s^(pos&7)
  __shared__ __align__(16) char Bl[2][2 * 64 * 128];// dbuf [2 taps][n][64ch], swz s^(n&7)
  int tid = threadIdx.x;
  int bx = blockIdx.x;
  int b = bx >> 6, tr = (bx >> 3) & 7, tc = bx & 7;
  int n0 = blockIdx.y << 6;
  int lane = tid & 63, wave = tid >> 6;
  int lr = lane & 15, lg = lane >> 4;

  float wA[4], wB[4], bb[4];
#pragma unroll
  for (int ni = 0; ni < 4; ++ni) {
    int n = n0 + (ni << 4) + lr;
    wA[ni] = W0[3200 * 256 + n];
    wB[ni] = W0[3201 * 256 + n];
    bb[ni] = b0[n];
  }

  // pair p (0..51): q=(5p)>>6, j=p-13q, taps f=2j(,2j+1 if j<12), cb=q&1
  int4v breg[4];
  auto loadB = [&](int p) {
    int q = (p * 5) >> 6, j = p - q * 13;
    int f0 = j * 2, cb = q & 1;
    int n = tid >> 3, s = tid & 7;   // wait: need 512 chunks per tap half
#pragma unroll
    for (int jj = 0; jj < 2; ++jj) {
      int idx = jj * 256 + tid;
      int nn = idx >> 3, ss = idx & 7;
      breg[jj] = *(const int4v*)(wt2 + (size_t)(f0 * 256 + n0 + nn) * 128 + cb * 64 + ss * 8);
    }
    if (j < 12) {
#pragma unroll
      for (int jj = 0; jj < 2; ++jj) {
        int idx = jj * 256 + tid;
        int nn = idx >> 3, ss = idx & 7;
        breg[2 + jj] = *(const int4v*)(wt2 + (size_t)((f0 + 1) * 256 + n0 + nn) * 128 + cb * 64 + ss * 8);
      }
    }
    (void)n; (void)s;
  };
  auto writeB = [&](int p) {
    int q = (p * 5) >> 6, j = p - q * 13;
    char* dst = Bl[p & 1];
#pragma unroll
    for (int jj = 0; jj < 2; ++jj) {
      int idx = jj * 256 + tid;
      int nn = idx >> 3, ss = idx & 7;
      *(int4v*)(dst + nn * 128 + ((ss ^ (nn & 7)) << 4)) = breg[jj];
    }
    if (j < 12) {
#pragma unroll
      for (int jj = 0; jj < 2; ++jj) {
        int idx = jj * 256 + tid;
        int nn = idx >> 3, ss = idx & 7;
        *(int4v*)(dst + 8192 + nn * 128 + ((ss ^ (nn & 7)) << 4)) = breg[2 + jj];
      }
    }
  };

  loadB(0);
  writeB(0);
  loadB(1);

  f32x4 acc[2][4] = {};

  for (int q = 0; q < 4; ++q) {
    int rh = q >> 1, half = q & 1;
    // ---- stage A(rh, half)
    __syncthreads();
#pragma unroll
    for (int ii = 0; ii < 8; ++ii) {
      int idx = ii * 256 + tid;
      if (idx < 1920) {
        int pos = idx >> 3, s = idx & 7;
        int py = pos / 20, px_ = pos - py * 20;
        int gh = (tr << 4) + (rh << 3) + py - 2, gw = (tc << 4) + px_ - 2;
        int4v v = {0, 0, 0, 0};
        if ((unsigned)gh < 128u && (unsigned)gw < 128u)
          v = *(const int4v*)(xt + (((size_t)((b << 14) + (gh << 7) + gw)) << 7) + half * 64 + s * 8);
        *(int4v*)(Al + pos * 128 + ((s ^ (pos & 7)) << 4)) = v;
      }
    }
    __syncthreads();

    for (int j = 0; j < 13; ++j) {
      int p = q * 13 + j;
      if (p < 51) writeB(p + 1);
      if (p < 50) loadB(p + 2);
      int f0 = j * 2;
      int cnt = (j == 12) ? 1 : 2;
      char* base = Bl[p & 1];
      for (int ft = 0; ft < cnt; ++ft) {
        int f = f0 + ft;
        int fy = (f * 13) >> 6, fx = f - fy * 5;
        int px = lr + fx;
        char* Bbuf = base + ft * 8192;
#pragma unroll
        for (int ks = 0; ks < 2; ++ks) {
          int sk = (ks << 2) + lg;
          bf16x8 a[2], bw[4];
#pragma unroll
          for (int mi = 0; mi < 2; ++mi) {
            int fl = wave + (mi << 2);
            int pos = (fl + fy) * 20 + px;
            a[mi] = *(const bf16x8*)(Al + pos * 128 + ((sk ^ (pos & 7)) << 4));
          }
#pragma unroll
          for (int ni = 0; ni < 4; ++ni) {
            int nr = (ni << 4) + lr;
            bw[ni] = *(const bf16x8*)(Bbuf + nr * 128 + ((sk ^ (nr & 7)) << 4));
          }
#pragma unroll
          for (int mi = 0; mi < 2; ++mi)
#pragma unroll
            for (int ni = 0; ni < 4; ++ni)
              acc[mi][ni] = __builtin_amdgcn_mfma_f32_16x16x32_bf16(a[mi], bw[ni], acc[mi][ni], 0, 0, 0);
        }
      }
      __syncthreads();
    }

    if (half == 1) {
      // ---- epilogue for this rh: bias+coords+sin, LDS bounce, coalesced stores
      char* stg = Al + wave * 4096;
#pragma unroll
      for (int mi = 0; mi < 2; ++mi) {
        int fl = wave + (mi << 2);
        int H = (tr << 4) + (rh << 3) + fl;
        float gy = -1.f + (2.f / 127.f) * (float)H;
#pragma unroll
        for (int j = 0; j < 4; ++j) {
          int cpx = (lg << 2) + j;
          int W = (tc << 4) + cpx;
          float gx = -1.f + (2.f / 127.f) * (float)W;
#pragma unroll
          for (int ni = 0; ni < 4; ++ni) {
            float v = acc[mi][ni][j] + bb[ni] + gx * wA[ni] + gy * wB[ni];
            unsigned short bits = f2bf(fast_sin30(v));
            int n = (ni << 4) + lr;
            int c = n >> 3;
            *(unsigned short*)(stg + mi * 2048 + cpx * 128 + (((c ^ (cpx & 7)) << 4) | ((n & 7) << 1))) = bits;
          }
        }
      }
#pragma unroll
      for (int mi = 0; mi < 2; ++mi) {
        int fl = wave + (mi << 2);
        int H = (tr << 4) + (rh << 3) + fl;
#pragma unroll
        for (int i2 = 0; i2 < 2; ++i2) {
          int r2 = (i2 << 3) + (lane >> 3);
          int c = lane & 7;
          int4v v = *(const int4v*)(stg + mi * 2048 + r2 * 128 + ((c ^ (r2 & 7)) << 4));
          int m = (b << 14) + (H << 7) + (tc << 4) + r2;
          *(int4v*)(h0 + (size_t)m * 256 + n0 + c * 8) = v;
        }
      }
      if (rh == 0) {
#pragma unroll
        for (int mi = 0; mi < 2; ++mi)
#pragma unroll
          for (int ni = 0; ni < 4; ++ni)
            acc[mi][ni] = f32x4{0.f, 0.f, 0.f, 0.f};
      }
    }
  }
}

// ---------------- fused MLP: h0 -> L1 -> L2 -> head (round-10, proven) ----------------
__global__ __launch_bounds__(256, 4) void k_fused(const __hip_bfloat16* __restrict__ h0,
                                                  const __hip_bfloat16* __restrict__ w1t,
                                                  const float* __restrict__ b1,
                                                  const __hip_bfloat16* __restrict__ w2t,
                                                  const float* __restrict__ b2,
                                                  const float* __restrict__ W3,
                                                  const float* __restrict__ b3,
                                                  float* __restrict__ out) {
  __shared__ __align__(16) char Hl[32 * 512];  // [r][slot sl^(r&31)][8 bf16]
  __shared__ float w3l[768];
  int tid = threadIdx.x;
  int m0 = blockIdx.x << 5;
  int lane = tid & 63, wave = tid >> 6;
  int lr = lane & 15, lg = lane >> 4;
  int mg = wave >> 1, nh = wave & 1;

  for (int i = tid; i < 768; i += 256) w3l[i] = W3[i];

  int mrow = m0 + (mg << 4) + lr;
  const char* pA0 = (const char*)(h0 + ((size_t)mrow << 8)) + (lg << 4);
  const char* pB1[8];
  const char* pB2[8];
  float bb1[8], bb2[8];
#pragma unroll
  for (int ni = 0; ni < 8; ++ni) {
    int n = (nh << 7) + (ni << 4) + lr;
    pB1[ni] = (const char*)(w1t + ((size_t)n << 8)) + (lg << 4);
    pB2[ni] = (const char*)(w2t + ((size_t)n << 8)) + (lg << 4);
    bb1[ni] = b1[n];
    bb2[ni] = b2[n];
  }

  f32x4 acc[8] = {};
#pragma unroll
  for (int ks = 0; ks < 8; ++ks) {
    bf16x8 a = *(const bf16x8*)(pA0 + ks * 64);
    bf16x8 bw[8];
#pragma unroll
    for (int ni = 0; ni < 8; ++ni) bw[ni] = *(const bf16x8*)(pB1[ni] + ks * 64);
#pragma unroll
    for (int ni = 0; ni < 8; ++ni)
      acc[ni] = __builtin_amdgcn_mfma_f32_16x16x32_bf16(a, bw[ni], acc[ni], 0, 0, 0);
  }
#pragma unroll
  for (int j = 0; j < 4; ++j) {
    int r = (mg << 4) + (lg << 2) + j;
#pragma unroll
    for (int ni = 0; ni < 8; ++ni) {
      int c = (nh << 7) + (ni << 4) + lr;
      unsigned short bits = f2bf(fast_sin30(acc[ni][j] + bb1[ni]));
      int sl = (c >> 3) ^ (r & 31);
      *(unsigned short*)(Hl + r * 512 + (sl << 4) + ((c & 7) << 1)) = bits;
    }
  }
  __syncthreads();

  int rA = (mg << 4) + lr;
  f32x4 acc2[8] = {};
#pragma unroll
  for (int ks = 0; ks < 8; ++ks) {
    int sk = (ks << 2) + lg;
    bf16x8 a = *(const bf16x8*)(Hl + rA * 512 + ((sk ^ (rA & 31)) << 4));
    bf16x8 bw[8];
#pragma unroll
    for (int ni = 0; ni < 8; ++ni) bw[ni] = *(const bf16x8*)(pB2[ni] + ks * 64);
#pragma unroll
    for (int ni = 0; ni < 8; ++ni)
      acc2[ni] = __builtin_amdgcn_mfma_f32_16x16x32_bf16(a, bw[ni], acc2[ni], 0, 0, 0);
  }
  __syncthreads();
#pragma unroll
  for (int j = 0; j < 4; ++j) {
    int r = (mg << 4) + (lg << 2) + j;
#pragma unroll
    for (int ni = 0; ni < 8; ++ni) {
      int c = (nh << 7) + (ni << 4) + lr;
      unsigned short bits = f2bf(fast_sin30(acc2[ni][j] + bb2[ni]));
      int sl = (c >> 3) ^ (r & 31);
      *(unsigned short*)(Hl + r * 512 + (sl << 4) + ((c & 7) << 1)) = bits;
    }
  }
  __syncthreads();

  int pix = tid >> 3, s = tid & 7;
  float a0 = 0.f, a1 = 0.f, a2 = 0.f;
#pragma unroll
  for (int q = 0; q < 4; ++q) {
    int sl = ((s << 2) + q) ^ (pix & 31);
    bf16x8 hv = *(const bf16x8*)(Hl + pix * 512 + (sl << 4));
#pragma unroll
    for (int e = 0; e < 8; ++e) {
      int k = (s << 5) + (q << 3) + e;
      float h = __uint_as_float((unsigned)(unsigned short)hv[e] << 16);
      a0 += h * w3l[k * 3 + 0];
      a1 += h * w3l[k * 3 + 1];
      a2 += h * w3l[k * 3 + 2];
    }
  }
#pragma unroll
  for (int d = 1; d < 8; d <<= 1) {
    a0 += __shfl_xor(a0, d);
    a1 += __shfl_xor(a1, d);
    a2 += __shfl_xor(a2, d);
  }
  if (s < 3) {
    int m = m0 + pix;
    int b = m >> 14, hw = m & 16383;
    float v = (s == 0) ? (a0 + b3[0]) : (s == 1) ? (a1 + b3[1]) : (a2 + b3[2]);
    out[((b * 3 + s) << 14) + hw] = v;
  }
}

extern "C" void kernel_launch(void* const* d_in, const int* in_sizes, int n_in,
                              void* d_out, int out_size, void* d_ws, size_t ws_size,
                              hipStream_t stream) {
  const float* xi = (const float*)d_in[0];
  const float* W0 = (const float*)d_in[1];
  const float* b0 = (const float*)d_in[2];
  const float* W1 = (const float*)d_in[3];
  const float* b1 = (const float*)d_in[4];
  const float* W2 = (const float*)d_in[5];
  const float* b2 = (const float*)d_in[6];
  const float* W3 = (const float*)d_in[7];
  const float* b3 = (const float*)d_in[8];
  float* out = (float*)d_out;
  char* ws = (char*)d_ws;

  __hip_bfloat16* xt  = (__hip_bfloat16*)(ws + 0);          //  8,388,608 B
  __hip_bfloat16* wt2 = (__hip_bfloat16*)(ws + 8388608);    //  1,638,400 B
  __hip_bfloat16* w1t = (__hip_bfloat16*)(ws + 10027008);   //    131,072 B
  __hip_bfloat16* w2t = (__hip_bfloat16*)(ws + 10158080);   //    131,072 B
  __hip_bfloat16* h0  = (__hip_bfloat16*)(ws + 10289152);   // 16,777,216 B

  k_prep<<<1352, 256, 0, stream>>>(xi, W0, W1, W2, xt, wt2, w1t, w2t);
  k_conv<<<dim3(128, 4), 256, 0, stream>>>(xt, wt2, W0, b0, h0);
  k_fused<<<1024, 256, 0, stream>>>(h0, w1t, b1, w2t, b2, W3, b3, out);
}